// Round 3
// baseline (182.216 us; speedup 1.0000x reference)
//
#include <hip/hip_runtime.h>
#include <hip/hip_cooperative_groups.h>
#include <math.h>

namespace cg = cooperative_groups;

// n=16384 Gaussian points in 3D. Exact 12-NN (incl self) per point:
//   out[i] = b + ( (W·p_i)·(1 + 11/sqrt(2)) + 0.5 * sum_{11NN} W·|p_i - p_j| ) / 12
//
// R17: sort compute is ~10-15 µs but 4 dispatches cost ~8 µs/boundary of
// launch gap (invariant across R14-R16 restructures). Fuse the whole sort
// chain into ONE cooperative kernel (grid=48x1024, co-resident) with two
// grid.sync()s:
//   phase 1: partial LDS histograms (dim = bid/16, part = bid%16) -> gh
//   phase 2: blocks 0-2: sum 16 partials + 1-barrier wave-shuffle scan
//            -> cursor ENDS (query prefix sums) + bin STARTS (gcur)
//   phase 3: all blocks: scatter (3 global atomic claims + 3 float4 stores)
// Dispatches: 4 -> 2. Query kernel unchanged from R13 (68 µs verified,
// VALUBusy 48%, FETCH 3.2 MB):
//   one wave per query; best-axis slab; seed 768 around bin-estimated rank
//   -> u = 12th of 64 lane minima (valid UB of tau) -> extent from prefix
//   sums -> fixed-trip collect into 4-deep paired (d2,w) buffer -> 12-round
//   paired knockout (exact take-12) -> reduce. Rare overflow (wave-uniform)
//   -> exact med3 fallback over the same extent. Self contributes w=0.

#define NBINS  2048
#define PARTS  16
#define CMIN_  (-6.0f)
#define INVBW_ ((float)NBINS / 12.0f)
#define BLOCK  256
#define WPB    4
#define SEED   768
#define KK     12
#define CD     4
#define BIG    3.0e38f

__device__ __forceinline__ int bin_of(float x) {
  int b = (int)((x - CMIN_) * INVBW_);
  b = b < 0 ? 0 : b;
  b = b > NBINS - 1 ? NBINS - 1 : b;
  return b;
}

__device__ __forceinline__ float wave_min(float v) {
#pragma unroll
  for (int o = 1; o < 64; o <<= 1) v = fminf(v, __shfl_xor(v, o));
  return v;
}

// sorted ascending 4-deep paired insert (static indexing -> registers)
__device__ __forceinline__ void ins4(float (&qd)[CD], float (&qw)[CD],
                                     float d, float w) {
#pragma unroll
  for (int k = CD - 1; k >= 1; --k) {
    const bool up  = (qd[k - 1] > d);
    const bool mid = (qd[k] > d);
    const float nd = up ? qd[k - 1] : (mid ? d : qd[k]);
    const float nw = up ? qw[k - 1] : (mid ? w : qw[k]);
    qd[k] = nd; qw[k] = nw;
  }
  if (qd[0] > d) { qw[0] = w; qd[0] = d; }
}

// ---------------- K1: fused hist + scan + scatter (cooperative, grid=48) ----
__global__ __launch_bounds__(1024)
void sort_fused(const float* __restrict__ p, int* __restrict__ gh,
                int* __restrict__ c_all, int* __restrict__ gcur,
                float4* __restrict__ s_all, int n) {
  cg::grid_group grid = cg::this_grid();
  __shared__ int h[NBINS];
  __shared__ int wsum[16];
  const int tid = threadIdx.x;
  const int bid = blockIdx.x;

  // ---- phase 1: partial histograms ----
  {
    const int dim  = bid / PARTS;
    const int part = bid % PARTS;
    h[tid] = 0; h[tid + 1024] = 0;
    __syncthreads();
    const int chunk = (n + PARTS - 1) / PARTS;
    const int i1 = min((part + 1) * chunk, n);
    for (int i = part * chunk + tid; i < i1; i += 1024)
      atomicAdd(&h[bin_of(p[3 * i + dim])], 1);
    __syncthreads();
    int* __restrict__ outp = gh + ((size_t)dim * PARTS + part) * NBINS;
    outp[tid]        = h[tid];
    outp[tid + 1024] = h[tid + 1024];
  }
  __threadfence();
  grid.sync();

  // ---- phase 2: per-axis scan (blocks 0..2) ----
  if (bid < 3) {
    const int dim = bid;
    int* __restrict__ cursor = c_all + (size_t)dim * NBINS;
    int* __restrict__ start  = gcur  + (size_t)dim * NBINS;
    const int* __restrict__ base = gh + (size_t)dim * PARTS * NBINS;

    int a = 0, b = 0;
#pragma unroll
    for (int pp = 0; pp < PARTS; ++pp) {
      a += base[pp * NBINS + 2 * tid];
      b += base[pp * NBINS + 2 * tid + 1];
    }
    const int v = a + b;
    const int lane = tid & 63, wid = tid >> 6;     // 16 waves
    int incl = v;
#pragma unroll
    for (int o = 1; o < 64; o <<= 1) {
      const int t = __shfl_up(incl, o);
      if (lane >= o) incl += t;
    }
    if (lane == 63) wsum[wid] = incl;
    __syncthreads();
    int woff = 0;
    for (int wI = 0; wI < wid; ++wI) woff += wsum[wI];   // broadcast reads
    const int excl = woff + incl - v;

    start[2 * tid]      = excl;
    start[2 * tid + 1]  = excl + a;
    cursor[2 * tid]     = excl + a;
    cursor[2 * tid + 1] = excl + a + b;
  }
  __threadfence();
  grid.sync();

  // ---- phase 3: scatter (all blocks; one point per thread) ----
  {
    const int i = bid * 1024 + tid;
    if (i < n) {
      const float x = p[3 * i], y = p[3 * i + 1], z = p[3 * i + 2];
      const float4 val = make_float4(x, y, z, __int_as_float(i));
      const int px = atomicAdd(&gcur[bin_of(x)], 1);
      const int py = atomicAdd(&gcur[NBINS + bin_of(y)], 1);
      const int pz = atomicAdd(&gcur[2 * NBINS + bin_of(z)], 1);
      s_all[px]         = val;
      s_all[n + py]     = val;
      s_all[2 * n + pz] = val;
    }
  }
}

// ---------------- K2: query (one wave per query, best-axis extent) -----------
__global__ __launch_bounds__(BLOCK)
void query_kernel(const float4* __restrict__ sx, const float4* __restrict__ sy,
                  const float4* __restrict__ sz, const int* __restrict__ cx,
                  const int* __restrict__ cy, const int* __restrict__ cz,
                  const float* __restrict__ W, const float* __restrict__ bias,
                  float* __restrict__ out, int n) {
  const int lane = threadIdx.x & 63;
  const int wv   = threadIdx.x >> 6;
  const int t    = wv * (n >> 2) + blockIdx.x;     // quartile interleave
  const float W0 = W[0], W1 = W[1], W2 = W[2];
  const float bb = bias[0];

  const float4 me = sx[t];                          // enumerate via x-sorted
  const float xi = me.x, yi = me.y, zi = me.z;
  const int orig = __float_as_int(me.w);

  // ---- choose axis with max |coord| (wave-uniform) ----
  const float ax = fabsf(xi), ay = fabsf(yi), az = fabsf(zi);
  const float4* sv; const int* cur; float cq;
  if (ay >= ax && ay >= az)      { sv = sy; cur = cy; cq = yi; }
  else if (az >= ax && az >= ay) { sv = sz; cur = cz; cq = zi; }
  else                           { sv = sx; cur = cx; cq = xi; }

  // ---- bin-estimated rank -> seed window ----
  const int bq = bin_of(cq);
  const int bs = (bq > 0) ? cur[bq - 1] : 0;
  const int be = cur[bq];
  int lo = ((bs + be) >> 1) - SEED / 2;
  lo = lo < 0 ? 0 : lo;
  lo = lo > n - SEED ? n - SEED : lo;
  const float4* base = sv + lo + lane;

  // ---- 1. seed lane-minima ----
  float m = BIG;
#pragma unroll
  for (int s = 0; s < SEED / 64; ++s) {
    const float4 c = base[s * 64];
    const float dx = xi - c.x, dy = yi - c.y, dz = zi - c.z;
    m = fminf(m, fmaf(dx, dx, fmaf(dy, dy, dz * dz)));
  }

  // ---- 2. u = 12th smallest of the 64 lane minima ----
  float u;
  {
    float v = m;
#pragma unroll
    for (int r = 0; r < KK; ++r) {
      const float mm = wave_min(v);
      u = mm;
      v = (v == mm) ? BIG : v;
    }
  }

  // ---- 3. extent from prefix sums: {|c - cq| <= sqrt(u)} ⊆ [lo2, hi2) ----
  const float s = sqrtf(u);
  const int bl = bin_of(cq - s);
  const int bh = bin_of(cq + s);
  const int lo2 = (bl > 0) ? cur[bl - 1] : 0;
  const int hi2 = cur[bh];
  const int steps = (hi2 - lo2 + 63) >> 6;

  // ---- collect-scan: fixed-trip, break-free ----
  float qd[CD], qw[CD];
  int ccnt = 0;
#pragma unroll
  for (int k = 0; k < CD; ++k) { qd[k] = BIG; qw[k] = 0.f; }

  int st = 0;
  for (; st + 2 <= steps; st += 2) {
    const int p0 = lo2 + st * 64 + lane;
    const int p1 = p0 + 64;
    const float4 c0 = sv[p0];
    const float4 c1 = sv[(p1 < hi2) ? p1 : hi2 - 1];
    {
      const float dx = xi - c0.x, dy = yi - c0.y, dz = zi - c0.z;
      const float d2 = fmaf(dx, dx, fmaf(dy, dy, dz * dz));
      if (d2 <= u) {
        const float w = fmaf(W0, fabsf(dx), fmaf(W1, fabsf(dy), W2 * fabsf(dz)));
        ++ccnt; ins4(qd, qw, d2, w);
      }
    }
    if (p1 < hi2) {
      const float dx = xi - c1.x, dy = yi - c1.y, dz = zi - c1.z;
      const float d2 = fmaf(dx, dx, fmaf(dy, dy, dz * dz));
      if (d2 <= u) {
        const float w = fmaf(W0, fabsf(dx), fmaf(W1, fabsf(dy), W2 * fabsf(dz)));
        ++ccnt; ins4(qd, qw, d2, w);
      }
    }
  }
  for (; st < steps; ++st) {
    const int pos = lo2 + st * 64 + lane;
    if (pos < hi2) {
      const float4 c = sv[pos];
      const float dx = xi - c.x, dy = yi - c.y, dz = zi - c.z;
      const float d2 = fmaf(dx, dx, fmaf(dy, dy, dz * dz));
      if (d2 <= u) {
        const float w = fmaf(W0, fabsf(dx), fmaf(W1, fabsf(dy), W2 * fabsf(dz)));
        ++ccnt; ins4(qd, qw, d2, w);
      }
    }
  }

  // ---- 4. extract exact 12 smallest ----
  float acc = 0.f;
  const bool ovf = __ballot(ccnt > CD) != 0ULL;   // wave-uniform
  if (!ovf) {
#pragma unroll
    for (int r = 0; r < KK; ++r) {
      const float mm = wave_min(qd[0]);
      const unsigned long long bal = __ballot(qd[0] == mm);
      if (qd[0] == mm && lane == (int)(__ffsll(bal) - 1)) {
        acc += qw[0];
#pragma unroll
        for (int k = 0; k < CD - 1; ++k) { qd[k] = qd[k + 1]; qw[k] = qw[k + 1]; }
        qd[CD - 1] = BIG;
      }
    }
  } else {
    // rare exact fallback over the same extent: med3 top-12 -> tau -> rescan
    float dd[KK];
#pragma unroll
    for (int k = 0; k < KK; ++k) dd[k] = BIG;
    for (int s0 = 0; s0 < steps; ++s0) {
      const int pos = lo2 + s0 * 64 + lane;
      const float4 c = sv[(pos < hi2) ? pos : hi2 - 1];
      const float dx = xi - c.x, dy = yi - c.y, dz = zi - c.z;
      const float d2 = (pos < hi2) ? fmaf(dx, dx, fmaf(dy, dy, dz * dz)) : BIG;
#pragma unroll
      for (int k = KK - 1; k >= 1; --k)
        dd[k] = __builtin_amdgcn_fmed3f(d2, dd[k - 1], dd[k]);
      dd[0] = fminf(dd[0], d2);
    }
    float tau = 0.f;
#pragma unroll
    for (int r = 0; r < KK; ++r) {
      const float mm = wave_min(dd[0]);
      if (dd[0] == mm) {
#pragma unroll
        for (int k = 0; k < KK - 1; ++k) dd[k] = dd[k + 1];
        dd[KK - 1] = BIG;
      }
      tau = mm;
    }
    for (int s0 = 0; s0 < steps; ++s0) {
      const int pos = lo2 + s0 * 64 + lane;
      if (pos < hi2) {
        const float4 c = sv[pos];
        const float dx = xi - c.x, dy = yi - c.y, dz = zi - c.z;
        const float d2 = fmaf(dx, dx, fmaf(dy, dy, dz * dz));
        const float w  = fmaf(W0, fabsf(dx), fmaf(W1, fabsf(dy), W2 * fabsf(dz)));
        acc += (d2 <= tau) ? w : 0.f;
      }
    }
  }

  // ---- 5. reduce + write ----
#pragma unroll
  for (int o = 1; o < 64; o <<= 1) acc += __shfl_xor(acc, o);
  if (lane == 0) {
    const float xw0 = W0 * xi + W1 * yi + W2 * zi;
    // 1 + 11/sqrt(2)
    out[orig] = bb + (xw0 * 8.778174593052022f + 0.5f * acc) * (1.0f / 12.0f);
  }
}

extern "C" void kernel_launch(void* const* d_in, const int* in_sizes, int n_in,
                              void* d_out, int out_size, void* d_ws, size_t ws_size,
                              hipStream_t stream) {
  const float* p  = (const float*)d_in[0];
  const float* W  = (const float*)d_in[1];
  const float* bb = (const float*)d_in[2];
  float* out = (float*)d_out;

  int n = in_sizes[0] / 3;   // 16384

  // ws layout:
  //   c_all  @ 0                      : 3*2048 ints  (bin ENDS, query)
  //   s_all  @ 24KB                   : 3*n float4   (sorted arrays)
  //   gcur   @ 24KB + 48n             : 3*2048 ints  (bin STARTS, scatter)
  //   gh     @ 24KB + 48n + 24KB      : 3*16*2048 ints (partial hists)
  int*    c_all = (int*)d_ws;
  float4* s_all = (float4*)((char*)d_ws + 3 * NBINS * 4);
  int*    gcur  = (int*)((char*)d_ws + 3 * NBINS * 4 + (size_t)3 * n * 16);
  int*    gh    = gcur + 3 * NBINS;
  int*    cx = c_all;
  int*    cy = cx + NBINS;
  int*    cz = cy + NBINS;
  float4* sx = s_all;
  float4* sy = sx + n;
  float4* sz = sy + n;

  void* args[] = {(void*)&p, (void*)&gh, (void*)&c_all, (void*)&gcur,
                  (void*)&s_all, (void*)&n};
  hipLaunchCooperativeKernel((void*)sort_fused, dim3(3 * PARTS), dim3(1024),
                             args, 0, stream);
  query_kernel<<<n / WPB, BLOCK, 0, stream>>>(sx, sy, sz, cx, cy, cz, W, bb, out, n);
}

// Round 4
// 121.400 us; speedup vs baseline: 1.5010x; 1.5010x over previous
//
#include <hip/hip_runtime.h>
#include <math.h>

// n=16384 Gaussian points in 3D. Exact 12-NN (incl self) per point:
//   out[i] = b + ( (W·p_i)·(1 + 11/sqrt(2)) + 0.5 * sum_{11NN} W·|p_i - p_j| ) / 12
//
// R18: revert R17's cooperative launch (+52 µs — coop launch breaks graph
// capture / pays host launch cost). New: the ENTIRE sort in ONE plain
// dispatch with NO grid sync. Block (dim,part) is self-sufficient:
//   stream all of p once -> LDS h_all (full axis hist) + h_pre (hist of
//   indices < part*chunk, wave-uniform predicate); block-local wave-shuffle
//   scan of h_all; private scatter window per bin = excl[bin] + h_pre[bin]
//   (stable counting sort by (bin,part): windows partition each bin exactly,
//   no global cursors, no inter-block ordering assumed). part==0 blocks
//   also write cursor ENDS (query prefix sums). 48 blocks ~ 48 CUs;
//   redundant p streams are L2-resident (9 MB L2 traffic total).
// Dispatches: 2 total (sort, query). Query unchanged from R13 (68 µs
// verified, VALUBusy 48%, FETCH 3.2 MB):
//   one wave per query; best-axis slab; seed 768 around bin-estimated rank
//   -> u = 12th of 64 lane minima (valid UB of tau) -> extent from prefix
//   sums -> fixed-trip collect into 4-deep paired (d2,w) buffer -> 12-round
//   paired knockout (exact take-12) -> reduce. Rare overflow (wave-uniform)
//   -> exact med3 fallback over the same extent. Self contributes w=0.

#define NBINS  2048
#define PARTS  16
#define CMIN_  (-6.0f)
#define INVBW_ ((float)NBINS / 12.0f)
#define BLOCK  256
#define WPB    4
#define SEED   768
#define KK     12
#define CD     4
#define BIG    3.0e38f

__device__ __forceinline__ int bin_of(float x) {
  int b = (int)((x - CMIN_) * INVBW_);
  b = b < 0 ? 0 : b;
  b = b > NBINS - 1 ? NBINS - 1 : b;
  return b;
}

__device__ __forceinline__ float wave_min(float v) {
#pragma unroll
  for (int o = 1; o < 64; o <<= 1) v = fminf(v, __shfl_xor(v, o));
  return v;
}

// sorted ascending 4-deep paired insert (static indexing -> registers)
__device__ __forceinline__ void ins4(float (&qd)[CD], float (&qw)[CD],
                                     float d, float w) {
#pragma unroll
  for (int k = CD - 1; k >= 1; --k) {
    const bool up  = (qd[k - 1] > d);
    const bool mid = (qd[k] > d);
    const float nd = up ? qd[k - 1] : (mid ? d : qd[k]);
    const float nw = up ? qw[k - 1] : (mid ? w : qw[k]);
    qd[k] = nd; qw[k] = nw;
  }
  if (qd[0] > d) { qw[0] = w; qd[0] = d; }
}

// ---------------- K1: self-sufficient fused sort (grid = 3*PARTS, plain) ----
__global__ __launch_bounds__(1024)
void sort_kernel(const float* __restrict__ p, int* __restrict__ c_all,
                 float4* __restrict__ s_all, int n) {
  __shared__ int h_all[NBINS];   // full per-axis histogram
  __shared__ int h_pre[NBINS];   // hist of indices < myStart; later: cursors
  __shared__ int wsum[16];
  const int tid  = threadIdx.x;
  const int dim  = blockIdx.x / PARTS;
  const int part = blockIdx.x % PARTS;
  const int chunk   = (n + PARTS - 1) / PARTS;
  const int myStart = part * chunk;
  const int myEnd   = min(myStart + chunk, n);

  h_all[tid] = 0; h_all[tid + 1024] = 0;
  h_pre[tid] = 0; h_pre[tid + 1024] = 0;
  __syncthreads();

  // ---- stream all of p once: full hist + predecessor hist ----
  for (int i = tid; i < n; i += 1024) {
    const int b = bin_of(p[3 * i + dim]);
    atomicAdd(&h_all[b], 1);
    if (i < myStart) atomicAdd(&h_pre[b], 1);   // wave-uniform predicate
  }
  __syncthreads();

  // ---- exclusive scan over bin pairs (wave-shuffle, 1 barrier) ----
  const int a = h_all[2 * tid], b = h_all[2 * tid + 1];
  const int v = a + b;
  const int lane = tid & 63, wid = tid >> 6;     // 16 waves
  int incl = v;
#pragma unroll
  for (int o = 1; o < 64; o <<= 1) {
    const int t = __shfl_up(incl, o);
    if (lane >= o) incl += t;
  }
  if (lane == 63) wsum[wid] = incl;
  __syncthreads();
  int woff = 0;
  for (int wI = 0; wI < wid; ++wI) woff += wsum[wI];   // broadcast reads
  const int excl = woff + incl - v;                    // start of bin 2*tid

  // query prefix sums (bin ENDS) — once per dim
  if (part == 0) {
    int* __restrict__ cursor = c_all + (size_t)dim * NBINS;
    cursor[2 * tid]     = excl + a;
    cursor[2 * tid + 1] = excl + a + b;
  }

  // private scatter cursors: my part's start within each bin
  const int c0 = excl + h_pre[2 * tid];
  const int c1 = excl + a + h_pre[2 * tid + 1];
  __syncthreads();                 // all reads of h_pre done before overwrite
  h_pre[2 * tid]     = c0;
  h_pre[2 * tid + 1] = c1;
  __syncthreads();

  // ---- scatter my chunk (LDS atomic claims, stable by (bin,part)) ----
  float4* __restrict__ sorted = s_all + (size_t)dim * n;
  for (int i = myStart + tid; i < myEnd; i += 1024) {
    const float x = p[3 * i], y = p[3 * i + 1], z = p[3 * i + 2];
    const float c = (dim == 0) ? x : (dim == 1) ? y : z;
    const int pos = atomicAdd(&h_pre[bin_of(c)], 1);
    sorted[pos] = make_float4(x, y, z, __int_as_float(i));
  }
}

// ---------------- K2: query (one wave per query, best-axis extent) -----------
__global__ __launch_bounds__(BLOCK)
void query_kernel(const float4* __restrict__ sx, const float4* __restrict__ sy,
                  const float4* __restrict__ sz, const int* __restrict__ cx,
                  const int* __restrict__ cy, const int* __restrict__ cz,
                  const float* __restrict__ W, const float* __restrict__ bias,
                  float* __restrict__ out, int n) {
  const int lane = threadIdx.x & 63;
  const int wv   = threadIdx.x >> 6;
  const int t    = wv * (n >> 2) + blockIdx.x;     // quartile interleave
  const float W0 = W[0], W1 = W[1], W2 = W[2];
  const float bb = bias[0];

  const float4 me = sx[t];                          // enumerate via x-sorted
  const float xi = me.x, yi = me.y, zi = me.z;
  const int orig = __float_as_int(me.w);

  // ---- choose axis with max |coord| (wave-uniform) ----
  const float ax = fabsf(xi), ay = fabsf(yi), az = fabsf(zi);
  const float4* sv; const int* cur; float cq;
  if (ay >= ax && ay >= az)      { sv = sy; cur = cy; cq = yi; }
  else if (az >= ax && az >= ay) { sv = sz; cur = cz; cq = zi; }
  else                           { sv = sx; cur = cx; cq = xi; }

  // ---- bin-estimated rank -> seed window ----
  const int bq = bin_of(cq);
  const int bs = (bq > 0) ? cur[bq - 1] : 0;
  const int be = cur[bq];
  int lo = ((bs + be) >> 1) - SEED / 2;
  lo = lo < 0 ? 0 : lo;
  lo = lo > n - SEED ? n - SEED : lo;
  const float4* base = sv + lo + lane;

  // ---- 1. seed lane-minima ----
  float m = BIG;
#pragma unroll
  for (int s = 0; s < SEED / 64; ++s) {
    const float4 c = base[s * 64];
    const float dx = xi - c.x, dy = yi - c.y, dz = zi - c.z;
    m = fminf(m, fmaf(dx, dx, fmaf(dy, dy, dz * dz)));
  }

  // ---- 2. u = 12th smallest of the 64 lane minima ----
  float u;
  {
    float v = m;
#pragma unroll
    for (int r = 0; r < KK; ++r) {
      const float mm = wave_min(v);
      u = mm;
      v = (v == mm) ? BIG : v;
    }
  }

  // ---- 3. extent from prefix sums: {|c - cq| <= sqrt(u)} ⊆ [lo2, hi2) ----
  const float s = sqrtf(u);
  const int bl = bin_of(cq - s);
  const int bh = bin_of(cq + s);
  const int lo2 = (bl > 0) ? cur[bl - 1] : 0;
  const int hi2 = cur[bh];
  const int steps = (hi2 - lo2 + 63) >> 6;

  // ---- collect-scan: fixed-trip, break-free ----
  float qd[CD], qw[CD];
  int ccnt = 0;
#pragma unroll
  for (int k = 0; k < CD; ++k) { qd[k] = BIG; qw[k] = 0.f; }

  int st = 0;
  for (; st + 2 <= steps; st += 2) {
    const int p0 = lo2 + st * 64 + lane;
    const int p1 = p0 + 64;
    const float4 c0 = sv[p0];
    const float4 c1 = sv[(p1 < hi2) ? p1 : hi2 - 1];
    {
      const float dx = xi - c0.x, dy = yi - c0.y, dz = zi - c0.z;
      const float d2 = fmaf(dx, dx, fmaf(dy, dy, dz * dz));
      if (d2 <= u) {
        const float w = fmaf(W0, fabsf(dx), fmaf(W1, fabsf(dy), W2 * fabsf(dz)));
        ++ccnt; ins4(qd, qw, d2, w);
      }
    }
    if (p1 < hi2) {
      const float dx = xi - c1.x, dy = yi - c1.y, dz = zi - c1.z;
      const float d2 = fmaf(dx, dx, fmaf(dy, dy, dz * dz));
      if (d2 <= u) {
        const float w = fmaf(W0, fabsf(dx), fmaf(W1, fabsf(dy), W2 * fabsf(dz)));
        ++ccnt; ins4(qd, qw, d2, w);
      }
    }
  }
  for (; st < steps; ++st) {
    const int pos = lo2 + st * 64 + lane;
    if (pos < hi2) {
      const float4 c = sv[pos];
      const float dx = xi - c.x, dy = yi - c.y, dz = zi - c.z;
      const float d2 = fmaf(dx, dx, fmaf(dy, dy, dz * dz));
      if (d2 <= u) {
        const float w = fmaf(W0, fabsf(dx), fmaf(W1, fabsf(dy), W2 * fabsf(dz)));
        ++ccnt; ins4(qd, qw, d2, w);
      }
    }
  }

  // ---- 4. extract exact 12 smallest ----
  float acc = 0.f;
  const bool ovf = __ballot(ccnt > CD) != 0ULL;   // wave-uniform
  if (!ovf) {
#pragma unroll
    for (int r = 0; r < KK; ++r) {
      const float mm = wave_min(qd[0]);
      const unsigned long long bal = __ballot(qd[0] == mm);
      if (qd[0] == mm && lane == (int)(__ffsll(bal) - 1)) {
        acc += qw[0];
#pragma unroll
        for (int k = 0; k < CD - 1; ++k) { qd[k] = qd[k + 1]; qw[k] = qw[k + 1]; }
        qd[CD - 1] = BIG;
      }
    }
  } else {
    // rare exact fallback over the same extent: med3 top-12 -> tau -> rescan
    float dd[KK];
#pragma unroll
    for (int k = 0; k < KK; ++k) dd[k] = BIG;
    for (int s0 = 0; s0 < steps; ++s0) {
      const int pos = lo2 + s0 * 64 + lane;
      const float4 c = sv[(pos < hi2) ? pos : hi2 - 1];
      const float dx = xi - c.x, dy = yi - c.y, dz = zi - c.z;
      const float d2 = (pos < hi2) ? fmaf(dx, dx, fmaf(dy, dy, dz * dz)) : BIG;
#pragma unroll
      for (int k = KK - 1; k >= 1; --k)
        dd[k] = __builtin_amdgcn_fmed3f(d2, dd[k - 1], dd[k]);
      dd[0] = fminf(dd[0], d2);
    }
    float tau = 0.f;
#pragma unroll
    for (int r = 0; r < KK; ++r) {
      const float mm = wave_min(dd[0]);
      if (dd[0] == mm) {
#pragma unroll
        for (int k = 0; k < KK - 1; ++k) dd[k] = dd[k + 1];
        dd[KK - 1] = BIG;
      }
      tau = mm;
    }
    for (int s0 = 0; s0 < steps; ++s0) {
      const int pos = lo2 + s0 * 64 + lane;
      if (pos < hi2) {
        const float4 c = sv[pos];
        const float dx = xi - c.x, dy = yi - c.y, dz = zi - c.z;
        const float d2 = fmaf(dx, dx, fmaf(dy, dy, dz * dz));
        const float w  = fmaf(W0, fabsf(dx), fmaf(W1, fabsf(dy), W2 * fabsf(dz)));
        acc += (d2 <= tau) ? w : 0.f;
      }
    }
  }

  // ---- 5. reduce + write ----
#pragma unroll
  for (int o = 1; o < 64; o <<= 1) acc += __shfl_xor(acc, o);
  if (lane == 0) {
    const float xw0 = W0 * xi + W1 * yi + W2 * zi;
    // 1 + 11/sqrt(2)
    out[orig] = bb + (xw0 * 8.778174593052022f + 0.5f * acc) * (1.0f / 12.0f);
  }
}

extern "C" void kernel_launch(void* const* d_in, const int* in_sizes, int n_in,
                              void* d_out, int out_size, void* d_ws, size_t ws_size,
                              hipStream_t stream) {
  const float* p  = (const float*)d_in[0];
  const float* W  = (const float*)d_in[1];
  const float* bb = (const float*)d_in[2];
  float* out = (float*)d_out;

  const int n = in_sizes[0] / 3;   // 16384

  // ws layout:
  //   c_all @ 0     : 3*2048 ints  (bin ENDS, query prefix sums)
  //   s_all @ 24KB  : 3*n float4   (sorted arrays)
  int*    c_all = (int*)d_ws;
  float4* s_all = (float4*)((char*)d_ws + 3 * NBINS * 4);
  int*    cx = c_all;
  int*    cy = cx + NBINS;
  int*    cz = cy + NBINS;
  float4* sx = s_all;
  float4* sy = sx + n;
  float4* sz = sy + n;

  sort_kernel<<<3 * PARTS, 1024, 0, stream>>>(p, c_all, s_all, n);
  query_kernel<<<n / WPB, BLOCK, 0, stream>>>(sx, sy, sz, cx, cy, cz, W, bb, out, n);
}